// Round 4
// baseline (124.564 us; speedup 1.0000x reference)
//
#include <hip/hip_runtime.h>

// DWT db4, 6 levels, zero mode. x:[64, 262144] f32 ->
// concat(cA6, cD6, cD5, cD4, cD3, cD2, cD1) flat.
//
// R7: persistent blocks, 4 consecutive tiles each (grid 33x64), R3
// constants (TT=32, NT=256). LDS = stage S (E/O) + work W0 + W1 = 17KB
// -> 8 blocks/CU = 32 waves (full residency). Next tile's stage is
// global-loaded into REGISTERS before L1 and ds_written into S after the
// post-L1 barrier (T14 issue-early/write-late): stage latency hides
// under the cascade; only the block prologue pays it once.
// bar_lds (lgkmcnt-only) barriers keep nt detail stores in flight.
// Block 32 handles edge tiles p=0,128 with the R3 slow path.

#define NT 256
#define TT 32
#define ITERS 4

#define N0 262144
#define M1 131075
#define M2 65541
#define M3 32774
#define M4 16390
#define M5 8198
#define M6 4102

#define LEN1 1210
#define LEN2 602
#define LEN3 298
#define LEN4 146
#define LEN5 70

#define NC1 303
#define NC2 151
#define NC3 75
#define NC4 37
#define NC5 18

#define OFF_A6 ((size_t)0)
#define OFF_D6 ((size_t)262528)
#define OFF_D5 ((size_t)525056)
#define OFF_D4 ((size_t)1049728)
#define OFF_D3 ((size_t)2098688)
#define OFF_D2 ((size_t)4196224)
#define OFF_D1 ((size_t)8390848)

// LDS float layout (all bases multiples of 16 floats):
// S-E [0,1216) S-O [1216,2432)   stage (x), dead after L1
// W0-E [2432,3040) W0-O [3040,3648)  cA1, then cA3, then cA5
// W1-E [3648,3952) W1-O [3952,4256)  cA2, then cA4
#define SE 0
#define SO 1216
#define W0E 2432
#define W0O 3040
#define W1E 3648
#define W1O 3952
#define LDS_FLOATS 4256

__device__ __constant__ float RLO[8] = {
    0.23037781330885523f, 0.7148465705525415f, 0.6308807679295904f,
    -0.02798376941698385f, -0.18703481171888114f, 0.030841381835986965f,
    0.032883011666982945f, -0.010597401784997278f};
__device__ __constant__ float RHI[8] = {
    -0.010597401784997278f, -0.032883011666982945f, 0.030841381835986965f,
    0.18703481171888114f, -0.02798376941698385f, -0.6308807679295904f,
    0.7148465705525415f, -0.23037781330885523f};

// LDS-only barrier: order LDS ops + sync waves; global nt stores stay in
// flight (drained at endpgm).
__device__ __forceinline__ void bar_lds() {
  asm volatile("s_waitcnt lgkmcnt(0)" ::: "memory");
  __builtin_amdgcn_s_barrier();
}

// One level: src de-interleaved (sE4/sO4), dst de-interleaved (dE2/dO2),
// details -> global nt. SHIFT=1 for level 1 (stage starts 2 floats before
// the window base), 0 otherwise.
template <int LEN, int NC, int SHIFT>
__device__ __forceinline__ void level_fast(const float4* __restrict__ sE4,
                                           const float4* __restrict__ sO4,
                                           float2* __restrict__ dE2,
                                           float2* __restrict__ dO2,
                                           float* __restrict__ dg) {
  for (int c = threadIdx.x; c < NC; c += NT) {
    float4 e0 = sE4[c], e1 = sE4[c + 1];
    float4 o0 = sO4[c], o1 = sO4[c + 1];
    float e[8] = {e0.x, e0.y, e0.z, e0.w, e1.x, e1.y, e1.z, e1.w};
    float o[8] = {o0.x, o0.y, o0.z, o0.w, o1.x, o1.y, o1.z, o1.w};
    float a[4], d[4];
#pragma unroll
    for (int j = 0; j < 4; ++j) {
      float aa = 0.f, dd = 0.f;
#pragma unroll
      for (int t = 0; t < 4; ++t) {
        float ev = e[j + t + SHIFT];
        float ov = o[j + t + SHIFT];
        aa = fmaf(RLO[2 * t], ev, aa);
        aa = fmaf(RLO[2 * t + 1], ov, aa);
        dd = fmaf(RHI[2 * t], ev, dd);
        dd = fmaf(RHI[2 * t + 1], ov, dd);
      }
      a[j] = aa;
      d[j] = dd;
    }
    dE2[c] = make_float2(a[0], a[2]);
    dO2[c] = make_float2(a[1], a[3]);
    const int l0 = 4 * c;
    if (l0 + 4 <= LEN) {
#pragma unroll
      for (int j = 0; j < 4; ++j) __builtin_nontemporal_store(d[j], dg + l0 + j);
    } else {
#pragma unroll
      for (int j = 0; j < 4; ++j)
        if (l0 + j < LEN) __builtin_nontemporal_store(d[j], dg + l0 + j);
    }
  }
}

// slow path (edge tiles): flat layout, bounds-checked
__device__ inline void dwt_step_slow(const float* __restrict__ s,
                                     float* __restrict__ d, int base, int len,
                                     int M, int cOff, float* __restrict__ dglob,
                                     int tid) {
  for (int l = tid; l < len; l += NT) {
    int g = base + l;
    float a = 0.f, dt = 0.f;
    if (g >= 0 && g < M) {
#pragma unroll
      for (int m = 0; m < 8; ++m) {
        float v = s[2 * l + m];
        a = fmaf(RLO[m], v, a);
        dt = fmaf(RHI[m], v, dt);
      }
    }
    d[l] = a;
    if (l >= cOff && g < M) dglob[g] = dt;
  }
}

__global__ __launch_bounds__(NT, 8) void dwt6_kernel(
    const float* __restrict__ x, float* __restrict__ out) {
  const int px = blockIdx.x;
  const int row = blockIdx.y;
  const int tid = threadIdx.x;

  __shared__ __align__(16) float lds[LDS_FLOATS];

  const float* __restrict__ xr = x + (size_t)row * N0;
  const size_t r1 = (size_t)row * M1, r2 = (size_t)row * M2,
               r3 = (size_t)row * M3, r4 = (size_t)row * M4,
               r5 = (size_t)row * M5, r6 = (size_t)row * M6;

  if (px < 32) {
    // ---- persistent fast path: tiles p = 1+4*px .. 1+4*px+3 (<=127) ----
    float2* sE2 = (float2*)(lds + SE);
    float2* sO2 = (float2*)(lds + SO);
    const float4* sE4 = (const float4*)(lds + SE);
    const float4* sO4 = (const float4*)(lds + SO);
    float2* w0E2 = (float2*)(lds + W0E);
    float2* w0O2 = (float2*)(lds + W0O);
    float2* w1E2 = (float2*)(lds + W1E);
    float2* w1O2 = (float2*)(lds + W1O);
    const float4* w0E4 = (const float4*)(lds + W0E);
    const float4* w0O4 = (const float4*)(lds + W0O);
    const float4* w1E4 = (const float4*)(lds + W1E);
    const float4* w1O4 = (const float4*)(lds + W1O);

    const int p0 = 1 + ITERS * px;

    // prologue: stage tile p0 (load -> regs -> LDS; one-time stall)
    {
      const float4* __restrict__ xs4 = (const float4*)(xr + (2048 * p0 - 380));
      float4 v0 = xs4[tid];
      float4 v1, v2;
      if (tid < 351) v1 = xs4[tid + 256];
      if (tid < 95) v2 = xs4[tid + 512];
      sE2[tid] = make_float2(v0.x, v0.z);
      sO2[tid] = make_float2(v0.y, v0.w);
      if (tid < 351) {
        sE2[tid + 256] = make_float2(v1.x, v1.z);
        sO2[tid + 256] = make_float2(v1.y, v1.w);
      }
      if (tid < 95) {
        sE2[tid + 512] = make_float2(v2.x, v2.z);
        sO2[tid + 512] = make_float2(v2.y, v2.w);
      }
    }

#pragma unroll 1
    for (int k = 0; k < ITERS; ++k) {
      const int p = p0 + k;
      if (p > 127) break;
      const bool have_next = (k + 1 < ITERS) && (p + 1 <= 127);

      // issue next tile's stage loads early (T14 issue-early)
      float4 q0, q1, q2;
      if (have_next) {
        const float4* __restrict__ xn4 =
            (const float4*)(xr + (2048 * (p + 1) - 380));
        q0 = xn4[tid];
        if (tid < 351) q1 = xn4[tid + 256];
        if (tid < 95) q2 = xn4[tid + 512];
      }

      const int b6 = p * TT;
      const int b5 = 2 * b6 - 6;
      const int b4 = 2 * b5 - 6;
      const int b3 = 2 * b4 - 6;
      const int b2 = 2 * b3 - 6;
      const int b1 = 2 * b2 - 6;  // 1024p - 186

      bar_lds();  // S ready; W0 free (prev L6 readers done)

      level_fast<LEN1, NC1, 1>(sE4, sO4, w0E2, w0O2, out + OFF_D1 + r1 + b1);
      bar_lds();  // all waves done reading S; W0 visible

      // write-late: next tile's stage into S (overlaps L2..L6 compute)
      if (have_next) {
        sE2[tid] = make_float2(q0.x, q0.z);
        sO2[tid] = make_float2(q0.y, q0.w);
        if (tid < 351) {
          sE2[tid + 256] = make_float2(q1.x, q1.z);
          sO2[tid + 256] = make_float2(q1.y, q1.w);
        }
        if (tid < 95) {
          sE2[tid + 512] = make_float2(q2.x, q2.z);
          sO2[tid + 512] = make_float2(q2.y, q2.w);
        }
      }

      level_fast<LEN2, NC2, 0>(w0E4, w0O4, w1E2, w1O2,
                               out + OFF_D2 + r2 + b2);
      bar_lds();
      level_fast<LEN3, NC3, 0>(w1E4, w1O4, w0E2, w0O2,
                               out + OFF_D3 + r3 + b3);
      bar_lds();
      level_fast<LEN4, NC4, 0>(w0E4, w0O4, w1E2, w1O2,
                               out + OFF_D4 + r4 + b4);
      bar_lds();
      level_fast<LEN5, NC5, 0>(w1E4, w1O4, w0E2, w0O2,
                               out + OFF_D5 + r5 + b5);
      bar_lds();

      // level 6: 32 outputs from W0 (cA5), straight to global
      float* __restrict__ ga = out + OFF_A6 + r6 + b6;
      float* __restrict__ gd = out + OFF_D6 + r6 + b6;
      for (int c = tid; c < 8; c += NT) {
        float4 e0 = w0E4[c], e1 = w0E4[c + 1];
        float4 o0 = w0O4[c], o1 = w0O4[c + 1];
        float e[8] = {e0.x, e0.y, e0.z, e0.w, e1.x, e1.y, e1.z, e1.w};
        float o[8] = {o0.x, o0.y, o0.z, o0.w, o1.x, o1.y, o1.z, o1.w};
#pragma unroll
        for (int j = 0; j < 4; ++j) {
          float aa = 0.f, dd = 0.f;
#pragma unroll
          for (int t = 0; t < 4; ++t) {
            aa = fmaf(RLO[2 * t], e[j + t], aa);
            aa = fmaf(RLO[2 * t + 1], o[j + t], aa);
            dd = fmaf(RHI[2 * t], e[j + t], dd);
            dd = fmaf(RHI[2 * t + 1], o[j + t], dd);
          }
          __builtin_nontemporal_store(aa, ga + 4 * c + j);
          __builtin_nontemporal_store(dd, gd + 4 * c + j);
        }
      }
      // loop-top bar_lds orders L6 reads before next L1's W0 writes
    }
  } else {
    // ---- edge block: tiles p = 0 and p = 128, slow path ----
    float* A = lds;         // flat, LEN0=2426 <= 2432 (S region)
    float* B = lds + W0E;   // flat, LEN1=1210 <= 1216 (W0 region)
#pragma unroll 1
    for (int t = 0; t < 2; ++t) {
      const int p = (t == 0) ? 0 : 128;
      const int b6 = p * TT;
      const int b5 = 2 * b6 - 6;
      const int b4 = 2 * b5 - 6;
      const int b3 = 2 * b4 - 6;
      const int b2 = 2 * b3 - 6;
      const int b1 = 2 * b2 - 6;
      const int b0 = 2 * b1 - 6;  // 2048p - 378

      bar_lds();  // reuse of A/B across the two tiles
      for (int l = tid; l < 2426; l += NT) {
        int g = b0 + l;
        A[l] = (g >= 0 && g < N0) ? xr[g] : 0.0f;
      }
      bar_lds();

      dwt_step_slow(A, B, b1, LEN1, M1, 186, out + OFF_D1 + r1, tid);
      bar_lds();
      dwt_step_slow(B, A, b2, LEN2, M2, 90, out + OFF_D2 + r2, tid);
      bar_lds();
      dwt_step_slow(A, B, b3, LEN3, M3, 42, out + OFF_D3 + r3, tid);
      bar_lds();
      dwt_step_slow(B, A, b4, LEN4, M4, 18, out + OFF_D4 + r4, tid);
      bar_lds();
      dwt_step_slow(A, B, b5, LEN5, M5, 6, out + OFF_D5 + r5, tid);
      bar_lds();

      for (int l = tid; l < TT; l += NT) {
        int g = b6 + l;
        if (g < M6) {
          float a = 0.f, dt = 0.f;
#pragma unroll
          for (int m = 0; m < 8; ++m) {
            float v = B[2 * l + m];
            a = fmaf(RLO[m], v, a);
            dt = fmaf(RHI[m], v, dt);
          }
          out[OFF_A6 + r6 + g] = a;
          out[OFF_D6 + r6 + g] = dt;
        }
      }
    }
  }
}

extern "C" void kernel_launch(void* const* d_in, const int* in_sizes, int n_in,
                              void* d_out, int out_size, void* d_ws,
                              size_t ws_size, hipStream_t stream) {
  const float* x = (const float*)d_in[0];
  float* out = (float*)d_out;
  dim3 grid(33, 64);  // 32 persistent interior blocks (4 tiles) + 1 edge block
  dwt6_kernel<<<grid, NT, 0, stream>>>(x, out);
}

// Round 5
// 117.395 us; speedup vs baseline: 1.0611x; 1.0611x over previous
//
#include <hip/hip_runtime.h>

// DWT db4, 6 levels, zero mode. x:[64, 262144] f32 ->
// concat(cA6, cD6, cD5, cD4, cD3, cD2, cD1) flat.
//
// R8: wave-autonomous tiles, ZERO barriers in the fast path.
// Each wave owns one TT=16 tile: level 1 reads x straight from global
// (L3-resident; no LDS stage), levels 2-6 ping-pong through a private
// 4.6KB LDS slice; intra-wave LDS ordering via lgkmcnt fences only.
// 4 waves/block (NT=256) so the 16-workgroup/CU cap doesn't bite
// (R4 lesson); LDS 18.4KB/block -> 8 blocks/CU = 32 waves resident.
// NC chain extended (190/94/46/22/10) so every LDS value read is
// written; boundary extra outputs are exact (real-x, in-bounds for
// p<=254) -> unmasked stores, benign identical-value overlap races.
// Edge tiles p=0,255,256: one cooperative slow block (R3-style).

#define NT 256
#define TT 16

#define N0 262144
#define M1 131075
#define M2 65541
#define M3 32774
#define M4 16390
#define M5 8198
#define M6 4102

// extended chunk counts (4 outputs per chunk), derived top-down so each
// consumer only reads produced values:
#define NC1 190
#define NC2 94
#define NC3 46
#define NC4 22
#define NC5 10

// slow-path exact lens (len_k = 2*len_{k+1}+6, len6=16)
#define LEN0S 1402
#define LEN1S 698
#define LEN2S 346
#define LEN3S 170
#define LEN4S 82
#define LEN5S 38

#define OFF_A6 ((size_t)0)
#define OFF_D6 ((size_t)262528)
#define OFF_D5 ((size_t)525056)
#define OFF_D4 ((size_t)1049728)
#define OFF_D3 ((size_t)2098688)
#define OFF_D2 ((size_t)4196224)
#define OFF_D1 ((size_t)8390848)

// per-wave LDS slice (floats, all 16B-aligned):
// W0E [0,384) W0O [384,768)   cA1, then cA3, then cA5
// W1E [768,960) W1O [960,1152) cA2, then cA4
#define W0E 0
#define W0O 384
#define W1E 768
#define W1O 960
#define WSLICE 1152
#define LDS_FLOATS (4 * WSLICE)

__device__ __constant__ float RLO[8] = {
    0.23037781330885523f, 0.7148465705525415f, 0.6308807679295904f,
    -0.02798376941698385f, -0.18703481171888114f, 0.030841381835986965f,
    0.032883011666982945f, -0.010597401784997278f};
__device__ __constant__ float RHI[8] = {
    -0.010597401784997278f, -0.032883011666982945f, 0.030841381835986965f,
    0.18703481171888114f, -0.02798376941698385f, -0.6308807679295904f,
    0.7148465705525415f, -0.23037781330885523f};

// intra-wave LDS fence: order this wave's ds_write -> ds_read across
// levels. No s_barrier (waves are fully independent).
__device__ __forceinline__ void fence_lds() {
  asm volatile("s_waitcnt lgkmcnt(0)" ::: "memory");
}

template <int SHIFT>
__device__ __forceinline__ void conv8(const float e[8], const float o[8],
                                      float a[4], float d[4]) {
#pragma unroll
  for (int j = 0; j < 4; ++j) {
    float aa = 0.f, dd = 0.f;
#pragma unroll
    for (int t = 0; t < 4; ++t) {
      float ev = e[j + t + SHIFT];
      float ov = o[j + t + SHIFT];
      aa = fmaf(RLO[2 * t], ev, aa);
      aa = fmaf(RLO[2 * t + 1], ov, aa);
      dd = fmaf(RHI[2 * t], ev, dd);
      dd = fmaf(RHI[2 * t + 1], ov, dd);
    }
    a[j] = aa;
    d[j] = dd;
  }
}

// One mid level, per-wave: LDS E/O -> LDS E/O, details -> global nt.
template <int NC>
__device__ __forceinline__ void level_w(const float4* __restrict__ sE4,
                                        const float4* __restrict__ sO4,
                                        float2* __restrict__ dE2,
                                        float2* __restrict__ dO2,
                                        float* __restrict__ dg, int lane) {
  for (int c = lane; c < NC; c += 64) {
    float4 e0 = sE4[c], e1 = sE4[c + 1];
    float4 o0 = sO4[c], o1 = sO4[c + 1];
    float e[8] = {e0.x, e0.y, e0.z, e0.w, e1.x, e1.y, e1.z, e1.w};
    float o[8] = {o0.x, o0.y, o0.z, o0.w, o1.x, o1.y, o1.z, o1.w};
    float a[4], d[4];
    conv8<0>(e, o, a, d);
    dE2[c] = make_float2(a[0], a[2]);
    dO2[c] = make_float2(a[1], a[3]);
    const int l0 = 4 * c;
#pragma unroll
    for (int j = 0; j < 4; ++j) __builtin_nontemporal_store(d[j], dg + l0 + j);
  }
}

// slow path (edge tiles): flat layout, bounds-checked
__device__ inline void dwt_step_slow(const float* __restrict__ s,
                                     float* __restrict__ d, int base, int len,
                                     int M, int cOff, float* __restrict__ dglob,
                                     int tid) {
  for (int l = tid; l < len; l += NT) {
    int g = base + l;
    float a = 0.f, dt = 0.f;
    if (g >= 0 && g < M) {
#pragma unroll
      for (int m = 0; m < 8; ++m) {
        float v = s[2 * l + m];
        a = fmaf(RLO[m], v, a);
        dt = fmaf(RHI[m], v, dt);
      }
    }
    d[l] = a;
    if (l >= cOff && g < M) dglob[g] = dt;
  }
}

__global__ __launch_bounds__(NT, 8) void dwt6_kernel(
    const float* __restrict__ x, float* __restrict__ out) {
  const int px = blockIdx.x;
  const int row = blockIdx.y;
  const int tid = threadIdx.x;

  __shared__ __align__(16) float lds[LDS_FLOATS];

  const float* __restrict__ xr = x + (size_t)row * N0;
  const size_t r1 = (size_t)row * M1, r2 = (size_t)row * M2,
               r3 = (size_t)row * M3, r4 = (size_t)row * M4,
               r5 = (size_t)row * M5, r6 = (size_t)row * M6;

  if (px < 64) {
    // ---- fast path: each wave owns tile p, fully autonomous ----
    const int wv = tid >> 6;
    const int lane = tid & 63;
    const int p = 1 + 4 * px + wv;  // 1..256; 255/256 handled by slow block
    if (p > 254) return;

    float* __restrict__ W = lds + wv * WSLICE;
    float2* w0E2 = (float2*)(W + W0E);
    float2* w0O2 = (float2*)(W + W0O);
    float2* w1E2 = (float2*)(W + W1E);
    float2* w1O2 = (float2*)(W + W1O);
    const float4* w0E4 = (const float4*)(W + W0E);
    const float4* w0O4 = (const float4*)(W + W0O);
    const float4* w1E4 = (const float4*)(W + W1E);
    const float4* w1O4 = (const float4*)(W + W1O);

    const int b6 = 16 * p;
    const int b5 = 32 * p - 6;
    const int b4 = 64 * p - 18;
    const int b3 = 128 * p - 42;
    const int b2 = 256 * p - 90;
    const int b1 = 512 * p - 186;

    // ---- level 1: global (L3/L1-resident) -> LDS + cD1 ----
    {
      const float4* __restrict__ x4 = (const float4*)(xr + (1024 * p - 380));
      float* __restrict__ dg1 = out + OFF_D1 + r1 + b1;
      for (int c = lane; c < NC1; c += 64) {
        float4 q0 = x4[2 * c], q1 = x4[2 * c + 1];
        float4 q2 = x4[2 * c + 2], q3 = x4[2 * c + 3];
        float e[8] = {q0.x, q0.z, q1.x, q1.z, q2.x, q2.z, q3.x, q3.z};
        float o[8] = {q0.y, q0.w, q1.y, q1.w, q2.y, q2.w, q3.y, q3.w};
        float a[4], d[4];
        conv8<1>(e, o, a, d);
        w0E2[c] = make_float2(a[0], a[2]);
        w0O2[c] = make_float2(a[1], a[3]);
        const int l0 = 4 * c;
#pragma unroll
        for (int j = 0; j < 4; ++j)
          __builtin_nontemporal_store(d[j], dg1 + l0 + j);
      }
    }
    fence_lds();

    level_w<NC2>(w0E4, w0O4, w1E2, w1O2, out + OFF_D2 + r2 + b2, lane);
    fence_lds();
    level_w<NC3>(w1E4, w1O4, w0E2, w0O2, out + OFF_D3 + r3 + b3, lane);
    fence_lds();
    level_w<NC4>(w0E4, w0O4, w1E2, w1O2, out + OFF_D4 + r4 + b4, lane);
    fence_lds();
    level_w<NC5>(w1E4, w1O4, w0E2, w0O2, out + OFF_D5 + r5 + b5, lane);
    fence_lds();

    // ---- level 6: 16 outputs, lanes 0..3 ----
    if (lane < 4) {
      const int c = lane;
      float* __restrict__ ga = out + OFF_A6 + r6 + b6;
      float* __restrict__ gd = out + OFF_D6 + r6 + b6;
      float4 e0 = w0E4[c], e1 = w0E4[c + 1];
      float4 o0 = w0O4[c], o1 = w0O4[c + 1];
      float e[8] = {e0.x, e0.y, e0.z, e0.w, e1.x, e1.y, e1.z, e1.w};
      float o[8] = {o0.x, o0.y, o0.z, o0.w, o1.x, o1.y, o1.z, o1.w};
      float a[4], d[4];
      conv8<0>(e, o, a, d);
      const int l0 = 4 * c;
#pragma unroll
      for (int j = 0; j < 4; ++j) {
        __builtin_nontemporal_store(a[j], ga + l0 + j);
        __builtin_nontemporal_store(d[j], gd + l0 + j);
      }
    }
  } else {
    // ---- slow block: tiles p = 0, 255, 256, cooperative, barriers ----
    float* A = lds;           // LEN0S = 1402
    float* B = lds + 1408;    // LEN1S = 698; 1408+698 <= 4608
#pragma unroll 1
    for (int t = 0; t < 3; ++t) {
      const int p = (t == 0) ? 0 : (t == 1) ? 255 : 256;
      const int b6 = 16 * p;
      const int b5 = 32 * p - 6;
      const int b4 = 64 * p - 18;
      const int b3 = 128 * p - 42;
      const int b2 = 256 * p - 90;
      const int b1 = 512 * p - 186;
      const int b0 = 1024 * p - 378;
      const int c1 = (p == 0) ? 186 : 0;
      const int c2 = (p == 0) ? 90 : 0;
      const int c3 = (p == 0) ? 42 : 0;
      const int c4 = (p == 0) ? 18 : 0;
      const int c5 = (p == 0) ? 6 : 0;

      __syncthreads();  // protect A/B reuse across tiles
      for (int l = tid; l < LEN0S; l += NT) {
        int g = b0 + l;
        A[l] = (g >= 0 && g < N0) ? xr[g] : 0.0f;
      }
      __syncthreads();

      dwt_step_slow(A, B, b1, LEN1S, M1, c1, out + OFF_D1 + r1, tid);
      __syncthreads();
      dwt_step_slow(B, A, b2, LEN2S, M2, c2, out + OFF_D2 + r2, tid);
      __syncthreads();
      dwt_step_slow(A, B, b3, LEN3S, M3, c3, out + OFF_D3 + r3, tid);
      __syncthreads();
      dwt_step_slow(B, A, b4, LEN4S, M4, c4, out + OFF_D4 + r4, tid);
      __syncthreads();
      dwt_step_slow(A, B, b5, LEN5S, M5, c5, out + OFF_D5 + r5, tid);
      __syncthreads();

      for (int l = tid; l < TT; l += NT) {
        int g = b6 + l;
        if (g < M6) {
          float a = 0.f, dt = 0.f;
#pragma unroll
          for (int m = 0; m < 8; ++m) {
            float v = B[2 * l + m];
            a = fmaf(RLO[m], v, a);
            dt = fmaf(RHI[m], v, dt);
          }
          out[OFF_A6 + r6 + g] = a;
          out[OFF_D6 + r6 + g] = dt;
        }
      }
    }
  }
}

extern "C" void kernel_launch(void* const* d_in, const int* in_sizes, int n_in,
                              void* d_out, int out_size, void* d_ws,
                              size_t ws_size, hipStream_t stream) {
  const float* x = (const float*)d_in[0];
  float* out = (float*)d_out;
  dim3 grid(65, 64);  // 64 fast blocks (4 wave-tiles each) + 1 slow block
  dwt6_kernel<<<grid, NT, 0, stream>>>(x, out);
}